// Round 9
// baseline (5367.553 us; speedup 1.0000x reference)
//
#include <hip/hip_runtime.h>

#define NHID   128
#define NSTEPS 512
#define NSAMP  4096
#define SPB    16
#define BS     512
#define NBLK   (NSAMP / SPB)          // 256 blocks, 1 per CU
#define KL     20                     // k4-chunks of W staged in LDS (of 32)
#define SAMP_ELEMS (NSAMP * NSTEPS)
#define WT_ELEMS   (3 * NHID * NHID)  // packed weights, 196 KB

typedef float v2f __attribute__((ext_vector_type(2)));
typedef float v4f __attribute__((ext_vector_type(4)));

// packed fma with h in an SGPR pair (natural lo/hi), weight pair broadcast:
// PKL: acc.lo += w.lo*h.lo ; acc.hi += w.lo*h.hi   (weight LOW broadcast)
#define PKL(A, W, H) \
    asm("v_pk_fma_f32 %0, %1, %2, %0 op_sel:[0,0,0] op_sel_hi:[0,1,1]" \
        : "+v"(A) : "v"(W), "s"(H))
// PKH: acc.lo += w.hi*h.lo ; acc.hi += w.hi*h.hi   (weight HIGH broadcast)
#define PKH(A, W, H) \
    asm("v_pk_fma_f32 %0, %1, %2, %0 op_sel:[1,0,0] op_sel_hi:[1,1,1]" \
        : "+v"(A) : "v"(W), "s"(H))

template<int IMM>
__device__ __forceinline__ float swz(float x) {
    return __int_as_float(__builtin_amdgcn_ds_swizzle(__float_as_int(x), IMM));
}

template<int HI>
__device__ __forceinline__ void pkstep(v4f h, int l, v2f wz, v2f wr, v2f wh,
                                       v2f& az01, v2f& az23, v2f& ar01,
                                       v2f& ar23, v2f& ah01, v2f& ah23)
{
    const unsigned h0 = (unsigned)__builtin_amdgcn_readlane(__float_as_int(h.x), l);
    const unsigned h1 = (unsigned)__builtin_amdgcn_readlane(__float_as_int(h.y), l);
    const unsigned h2 = (unsigned)__builtin_amdgcn_readlane(__float_as_int(h.z), l);
    const unsigned h3 = (unsigned)__builtin_amdgcn_readlane(__float_as_int(h.w), l);
    const unsigned long long hp01 = (unsigned long long)h0 | ((unsigned long long)h1 << 32);
    const unsigned long long hp23 = (unsigned long long)h2 | ((unsigned long long)h3 << 32);
    if (HI) {
        PKH(az01, wz, hp01); PKH(az23, wz, hp23);
        PKH(ar01, wr, hp01); PKH(ar23, wr, hp23);
        PKH(ah01, wh, hp01); PKH(ah23, wh, hp23);
    } else {
        PKL(az01, wz, hp01); PKL(az23, wz, hp23);
        PKL(ar01, wr, hp01); PKL(ar23, wr, hp23);
        PKL(ah01, wh, hp01); PKL(ah23, wh, hp23);
    }
}

// wt[g][k4][c][j] = rk[(4*k4+j)*384 + g*128 + c]  (wave of 64 consecutive
// channels reads 1KB fully-unique contiguous per (g,k4))
__global__ __launch_bounds__(256)
void pack_w_kernel(const float* __restrict__ rk, float* __restrict__ wt) {
    const int i = blockIdx.x * 256 + threadIdx.x;
    if (i < WT_ELEMS) {
        const int j  = i & 3;
        const int c  = (i >> 2) & 127;
        const int k4 = (i >> 9) & 31;
        const int g  = i >> 14;
        wt[i] = rk[(k4 * 4 + j) * 384 + g * NHID + c];
    }
}

template<int TR>
__global__ __launch_bounds__(BS, 2)
void vmc_gru_kernel(const float* __restrict__ gk,   // (2, 384)
                    const float* __restrict__ rk,   // (128, 384)
                    const float* __restrict__ gb,   // (2, 384)
                    const float* __restrict__ dw,   // (128, 2)
                    const float* __restrict__ db,   // (2,)
                    const float* __restrict__ u,    // (4096, 512)
                    const float* __restrict__ wt,   // packed (3,32,128,4)
                    float* __restrict__ out)        // samples then logp
{
    __shared__ v4f   slds[3 * KL * NHID];     // 120 KB, W chunk [g][k4<KL][c]
    __shared__ float hsm[2][4][NHID][4];      // 16 KB, h[buf][quad][k][4 samples]
    __shared__ float part[2][8][4][8];        // 8 KB, [pb][wv][group][p0 x4, p1 x4]

    const int tid  = threadIdx.x;
    const int lane = tid & 63;
    const int wv   = tid >> 6;       // 0..7
    const int half = wv & 1;         // channel half
    const int q    = wv >> 1;        // quad 0..3
    const int c    = half * 64 + lane;   // this thread's channel
    const int sbase = blockIdx.x * SPB + q * 4;

    // ---- stage W chunk into LDS (once)
    if (TR) {
        const v4f* wt4 = (const v4f*)wt;
        for (int i = tid; i < 3 * KL * NHID; i += BS) {
            const int g = i / (KL * NHID);
            const int r = i - g * (KL * NHID);
            slds[i] = wt4[g * 4096 + r];
        }
    }
    for (int i = tid; i < 2 * 4 * NHID * 4; i += BS) (&hsm[0][0][0][0])[i] = 0.0f;
    __syncthreads();

    // per-channel constants
    const float brz = gb[384 + c];
    const float brr = gb[384 + 128 + c];
    const float brh = gb[384 + 256 + c];
    const float xzI = gb[c],       xz0c = xzI + gk[c],       xz1c = xzI + gk[384 + c];
    const float xrI = gb[128 + c], xr0c = xrI + gk[128 + c], xr1c = xrI + gk[384 + 128 + c];
    const float xhI = gb[256 + c], xh0c = xhI + gk[256 + c], xh1c = xhI + gk[384 + 256 + c];
    const float dwc0 = dw[c * 2], dwc1 = dw[c * 2 + 1];
    const float db0 = db[0], db1 = db[1];

    const v4f* lz = slds + c;
    const v4f* lr = slds + KL * 128 + c;
    const v4f* lh = slds + 2 * KL * 128 + c;
    const v4f* wz4 = (const v4f*)wt + c;
    const v4f* wr4 = (const v4f*)wt + 4096 + c;
    const v4f* wh4 = (const v4f*)wt + 8192 + c;
    const float* rkc = rk + c;

    int   pv[4] = {0, 0, 0, 0};
    float lg[4] = {0.f, 0.f, 0.f, 0.f};
    float pr[4] = {1.f, 1.f, 1.f, 1.f};
    int cur = 0;

    for (int t = 0; t < NSTEPS; ++t) {
        // prefetch u for this step (consumed after barrier)
        float uv[4];
        #pragma unroll
        for (int j = 0; j < 4; ++j)
            uv[j] = u[(size_t)(sbase + j) * NSTEPS + t];

        // cooperative h load: lane j holds h[k=j][quad] and h[k=64+j][quad]
        const v4f hA = *(const v4f*)&hsm[cur][q][lane][0];
        const v4f hB = *(const v4f*)&hsm[cur][q][64 + lane][0];

        v2f az01 = {brz, brz}, az23 = {brz, brz};
        v2f ar01 = {brr, brr}, ar23 = {brr, brr};
        v2f ah01 = {brh, brh}, ah23 = {brh, brh};

        if (TR) {
            #pragma unroll 4
            for (int k4 = 0; k4 < 16; ++k4) {          // W LDS, h from hA
                const v4f wzq = lz[k4 * 128];
                const v4f wrq = lr[k4 * 128];
                const v4f whq = lh[k4 * 128];
                const int kb = k4 * 4;
                pkstep<0>(hA, kb + 0, wzq.xy, wrq.xy, whq.xy, az01, az23, ar01, ar23, ah01, ah23);
                pkstep<1>(hA, kb + 1, wzq.xy, wrq.xy, whq.xy, az01, az23, ar01, ar23, ah01, ah23);
                pkstep<0>(hA, kb + 2, wzq.zw, wrq.zw, whq.zw, az01, az23, ar01, ar23, ah01, ah23);
                pkstep<1>(hA, kb + 3, wzq.zw, wrq.zw, whq.zw, az01, az23, ar01, ar23, ah01, ah23);
            }
            #pragma unroll 4
            for (int k4 = 16; k4 < KL; ++k4) {         // W LDS, h from hB
                const v4f wzq = lz[k4 * 128];
                const v4f wrq = lr[k4 * 128];
                const v4f whq = lh[k4 * 128];
                const int kb = k4 * 4 - 64;
                pkstep<0>(hB, kb + 0, wzq.xy, wrq.xy, whq.xy, az01, az23, ar01, ar23, ah01, ah23);
                pkstep<1>(hB, kb + 1, wzq.xy, wrq.xy, whq.xy, az01, az23, ar01, ar23, ah01, ah23);
                pkstep<0>(hB, kb + 2, wzq.zw, wrq.zw, whq.zw, az01, az23, ar01, ar23, ah01, ah23);
                pkstep<1>(hB, kb + 3, wzq.zw, wrq.zw, whq.zw, az01, az23, ar01, ar23, ah01, ah23);
            }
            #pragma unroll 4
            for (int k4 = KL; k4 < 32; ++k4) {         // W global (L1/L2), h from hB
                const v4f wzq = wz4[k4 * 128];
                const v4f wrq = wr4[k4 * 128];
                const v4f whq = wh4[k4 * 128];
                const int kb = k4 * 4 - 64;
                pkstep<0>(hB, kb + 0, wzq.xy, wrq.xy, whq.xy, az01, az23, ar01, ar23, ah01, ah23);
                pkstep<1>(hB, kb + 1, wzq.xy, wrq.xy, whq.xy, az01, az23, ar01, ar23, ah01, ah23);
                pkstep<0>(hB, kb + 2, wzq.zw, wrq.zw, whq.zw, az01, az23, ar01, ar23, ah01, ah23);
                pkstep<1>(hB, kb + 3, wzq.zw, wrq.zw, whq.zw, az01, az23, ar01, ar23, ah01, ah23);
            }
        } else {
            // fallback: scalar weights straight from rk
            #pragma unroll 4
            for (int k = 0; k < NHID; ++k) {
                const v4f hsrc = (k < 64) ? hA : hB;
                const int l = k & 63;
                float hh[4];
                hh[0] = __int_as_float(__builtin_amdgcn_readlane(__float_as_int(hsrc.x), l));
                hh[1] = __int_as_float(__builtin_amdgcn_readlane(__float_as_int(hsrc.y), l));
                hh[2] = __int_as_float(__builtin_amdgcn_readlane(__float_as_int(hsrc.z), l));
                hh[3] = __int_as_float(__builtin_amdgcn_readlane(__float_as_int(hsrc.w), l));
                const float wzs = rkc[k * 384];
                const float wrs = rkc[k * 384 + 128];
                const float whs = rkc[k * 384 + 256];
                float azs[4] = {az01.x, az01.y, az23.x, az23.y};
                float ars[4] = {ar01.x, ar01.y, ar23.x, ar23.y};
                float ahs[4] = {ah01.x, ah01.y, ah23.x, ah23.y};
                #pragma unroll
                for (int j = 0; j < 4; ++j) azs[j] = fmaf(wzs, hh[j], azs[j]);
                #pragma unroll
                for (int j = 0; j < 4; ++j) ars[j] = fmaf(wrs, hh[j], ars[j]);
                #pragma unroll
                for (int j = 0; j < 4; ++j) ahs[j] = fmaf(whs, hh[j], ahs[j]);
                az01 = (v2f){azs[0], azs[1]}; az23 = (v2f){azs[2], azs[3]};
                ar01 = (v2f){ars[0], ars[1]}; ar23 = (v2f){ars[2], ars[3]};
                ah01 = (v2f){ahs[0], ahs[1]}; ah23 = (v2f){ahs[2], ahs[3]};
            }
        }

        const float az[4] = {az01.x, az01.y, az23.x, az23.y};
        const float ar[4] = {ar01.x, ar01.y, ar23.x, ar23.y};
        const float ah[4] = {ah01.x, ah01.y, ah23.x, ah23.y};

        // ---- gates + state update (old h for this channel is hA or hB: free)
        const v4f ho = half ? hB : hA;
        const float hov[4] = {ho.x, ho.y, ho.z, ho.w};
        float hn[4], p0s[4], p1s[4];
        #pragma unroll
        for (int j = 0; j < 4; ++j) {
            float xz = pv[j] ? xz1c : xz0c;
            float xr = pv[j] ? xr1c : xr0c;
            float xh = pv[j] ? xh1c : xh0c;
            if (t == 0) { xz = xzI; xr = xrI; xh = xhI; }
            const float z  = 1.0f / (1.0f + expf(-(xz + az[j])));
            const float r  = 1.0f / (1.0f + expf(-(xr + ar[j])));
            const float hc = tanhf(xh + r * ah[j]);
            const float hnew = z * hov[j] + (1.0f - z) * hc;
            hn[j] = hnew;
            p0s[j] = hnew * dwc0;
            p1s[j] = hnew * dwc1;
        }
        *(v4f*)&hsm[cur ^ 1][q][c][0] = (v4f){hn[0], hn[1], hn[2], hn[3]};

        // butterfly over c-bits 0..3 (lane bits 0..3): same pairing/order as R8
        #pragma unroll
        for (int j = 0; j < 4; ++j) {
            p0s[j] += swz<0x041F>(p0s[j]);  p1s[j] += swz<0x041F>(p1s[j]);
            p0s[j] += swz<0x081F>(p0s[j]);  p1s[j] += swz<0x081F>(p1s[j]);
            p0s[j] += swz<0x101F>(p0s[j]);  p1s[j] += swz<0x101F>(p1s[j]);
            p0s[j] += swz<0x201F>(p0s[j]);  p1s[j] += swz<0x201F>(p1s[j]);
        }
        // now each 16-lane group holds T16 for channels [64*half+16g .. +16)
        const int pb = t & 1;
        if ((lane & 15) == 0) {
            const int g = lane >> 4;
            *(float4*)&part[pb][wv][g][0] = make_float4(p0s[0], p0s[1], p0s[2], p0s[3]);
            *(float4*)&part[pb][wv][g][4] = make_float4(p1s[0], p1s[1], p1s[2], p1s[3]);
        }
        __syncthreads();   // single barrier: h_new + partials visible

        // ---- fold 8 partials sequentially (w = 4*half' + g ascending: same as R8)
        float l0[4] = {db0, db0, db0, db0};
        float l1[4] = {db1, db1, db1, db1};
        #pragma unroll
        for (int w = 0; w < 8; ++w) {
            const int hw = w >> 2, g = w & 3;
            const float4 a = *(const float4*)&part[pb][q * 2 + hw][g][0];
            const float4 b = *(const float4*)&part[pb][q * 2 + hw][g][4];
            l0[0] += a.x; l0[1] += a.y; l0[2] += a.z; l0[3] += a.w;
            l1[0] += b.x; l1[1] += b.y; l1[2] += b.z; l1[3] += b.w;
        }

        // ---- softmax / sample / logp (redundant per thread, its quad's samples)
        #pragma unroll
        for (int j = 0; j < 4; ++j) {
            const float mx = fmaxf(l0[j], l1[j]);
            const float e0 = expf(l0[j] - mx);
            const float e1 = expf(l1[j] - mx);
            const float inv = 1.0f / (e0 + e1);
            const float p1v = e1 * inv;
            const int st = (uv[j] < p1v) ? 1 : 0;
            const float psel = st ? p1v : (e0 * inv);
            pr[j] *= (psel + 1e-10f);
            pv[j] = st;
            if (lane == 0 && half == 0)
                out[(size_t)(sbase + j) * NSTEPS + t] = (float)st;
        }
        if ((t & 7) == 7) {
            #pragma unroll
            for (int j = 0; j < 4; ++j) { lg[j] += logf(pr[j]); pr[j] = 1.0f; }
        }
        cur ^= 1;
    }

    if (lane == 0 && half == 0) {
        #pragma unroll
        for (int j = 0; j < 4; ++j)
            out[SAMP_ELEMS + sbase + j] = lg[j];
    }
}

extern "C" void kernel_launch(void* const* d_in, const int* in_sizes, int n_in,
                              void* d_out, int out_size, void* d_ws, size_t ws_size,
                              hipStream_t stream) {
    const float* gk = (const float*)d_in[0];
    const float* rk = (const float*)d_in[1];
    const float* gb = (const float*)d_in[2];
    const float* dw = (const float*)d_in[3];
    const float* db = (const float*)d_in[4];
    const float* u  = (const float*)d_in[5];
    float* out = (float*)d_out;

    if (ws_size >= (size_t)WT_ELEMS * sizeof(float)) {
        float* wt = (float*)d_ws;
        pack_w_kernel<<<(WT_ELEMS + 255) / 256, 256, 0, stream>>>(rk, wt);
        vmc_gru_kernel<1><<<NBLK, BS, 0, stream>>>(gk, rk, gb, dw, db, u, wt, out);
    } else {
        vmc_gru_kernel<0><<<NBLK, BS, 0, stream>>>(gk, rk, gb, dw, db, u, rk, out);
    }
}